// Round 8
// baseline (1314.043 us; speedup 1.0000x reference)
//
#include <hip/hip_runtime.h>
#include <hip/hip_bf16.h>
#include <hip/hip_fp16.h>

// Problem: B=64, S=512, E=768, H=256 (4H=1024). Bidirectional relu-LSTM + dense(2).
#define B_ 64
#define S_ 512
#define E_ 768
#define H_ 256
#define G_ 1024  // 4H
#define MROWS 32768  // B*S per direction

typedef float f32x4 __attribute__((ext_vector_type(4)));
typedef float f32x16 __attribute__((ext_vector_type(16)));
typedef short short8 __attribute__((ext_vector_type(8)));
typedef _Float16 v2h __attribute__((ext_vector_type(2)));
typedef unsigned int u32x4 __attribute__((ext_vector_type(4)));

// ---------------- prep kernels ----------------

__global__ void cast_x_kernel(const float* __restrict__ x, __hip_bfloat16* __restrict__ xbf, int n) {
    int i = (blockIdx.x * 256 + threadIdx.x) * 4;
    if (i >= n) return;
    float4 v = *(const float4*)(x + i);
    xbf[i + 0] = __float2bfloat16(v.x);
    xbf[i + 1] = __float2bfloat16(v.y);
    xbf[i + 2] = __float2bfloat16(v.z);
    xbf[i + 3] = __float2bfloat16(v.w);
}

// kernel [E][G] fp32 -> kT [dir][G][E] bf16 (transposed for MFMA B-fragments)
__global__ void prep_kT_kernel(const float* __restrict__ kf, const float* __restrict__ kb,
                               __hip_bfloat16* __restrict__ kT) {
    int idx = blockIdx.x * 256 + threadIdx.x;   // over E_*G_
    int dir = blockIdx.y;
    const float* src = dir ? kb : kf;
    int k = idx >> 10;        // E index
    int n = idx & 1023;       // G index
    float v = src[idx];       // coalesced read (n fast)
    kT[(size_t)dir * G_ * E_ + (size_t)n * E_ + k] = __float2bfloat16(v);
}

// rec [256][1024] fp32 -> recQ [dir][32][1024] uint4: half2 pairs of k = 8kk..8kk+7, col g
__global__ void prep_recQ_kernel(const float* __restrict__ rf, const float* __restrict__ rb,
                                 unsigned int* __restrict__ recQ) {
    int idx = blockIdx.x * 256 + threadIdx.x;   // over 32*1024*4 = 131072
    int dir = blockIdx.y;
    const float* src = dir ? rb : rf;
    int g  = idx & 1023;
    int u  = (idx >> 10) & 3;
    int kk = idx >> 12;
    int k0 = 8 * kk + 2 * u;
    float a = src[(size_t)k0 * G_ + g];
    float b = src[(size_t)(k0 + 1) * G_ + g];
    v2h p;
    p[0] = (_Float16)a;
    p[1] = (_Float16)b;
    recQ[(size_t)dir * 131072 + (size_t)kk * 4096 + g * 4 + u] = __builtin_bit_cast(unsigned int, p);
}

// ---------------- xz GEMM: LDS-tiled 128x128, BK=32, mfma 32x32x16 (unchanged) --------
#define TM 128
#define TN 128
#define BK 32
#define LDA 40   // padded LDS row stride in elements

__global__ __launch_bounds__(256) void gemm_xz_kernel(
        const __hip_bfloat16* __restrict__ xbf,   // [B*S][E]
        const __hip_bfloat16* __restrict__ kT,    // [2][G][E]
        const float* __restrict__ bias_f, const float* __restrict__ bias_b,
        __hip_bfloat16* __restrict__ xz) {        // [2][MROWS][G]
    int dir  = blockIdx.z;
    int nblk = blockIdx.x;      // 0..7   (G/128)
    int mblk = blockIdx.y;      // 0..255 (MROWS/128)
    int tid  = threadIdx.x;
    int wave = tid >> 6, lane = tid & 63;

    __shared__ __hip_bfloat16 shA[TM * LDA];
    __shared__ __hip_bfloat16 shB[TN * LDA];

    int m0 = mblk * TM;
    int n0 = nblk * TN;

    int rowl0 = tid >> 2;             // 0..63
    int rowl1 = rowl0 + 64;           // 64..127
    int k8    = (tid & 3) * 8;
    int ar0 = m0 + rowl0, ar1 = m0 + rowl1;
    int sa0 = (ar0 & ~511) | (dir ? (511 - (ar0 & 511)) : (ar0 & 511));
    int sa1 = (ar1 & ~511) | (dir ? (511 - (ar1 & 511)) : (ar1 & 511));
    const __hip_bfloat16* kbase = kT + (size_t)dir * G_ * E_;

    f32x16 acc[4] = {};

    int lm = lane & 31;
    int kq = (lane >> 5) * 8;

    for (int k0 = 0; k0 < E_; k0 += BK) {
        __syncthreads();
        *(short8*)&shA[rowl0 * LDA + k8] = *(const short8*)(xbf + (size_t)sa0 * E_ + k0 + k8);
        *(short8*)&shA[rowl1 * LDA + k8] = *(const short8*)(xbf + (size_t)sa1 * E_ + k0 + k8);
        *(short8*)&shB[rowl0 * LDA + k8] = *(const short8*)(kbase + (size_t)(n0 + rowl0) * E_ + k0 + k8);
        *(short8*)&shB[rowl1 * LDA + k8] = *(const short8*)(kbase + (size_t)(n0 + rowl1) * E_ + k0 + k8);
        __syncthreads();

#pragma unroll
        for (int kk = 0; kk < BK; kk += 16) {
            short8 afrag = *(const short8*)&shA[(wave * 32 + lm) * LDA + kk + kq];
#pragma unroll
            for (int j = 0; j < 4; ++j) {
                short8 bfrag = *(const short8*)&shB[(j * 32 + lm) * LDA + kk + kq];
                acc[j] = __builtin_amdgcn_mfma_f32_32x32x16_bf16(afrag, bfrag, acc[j], 0, 0, 0);
            }
        }
    }

    const float* bias = dir ? bias_b : bias_f;
#pragma unroll
    for (int j = 0; j < 4; ++j) {
        int col = n0 + j * 32 + lm;
        float bv = bias[col];
#pragma unroll
        for (int reg = 0; reg < 16; ++reg) {
            int row = m0 + wave * 32 + (reg & 3) + 8 * (reg >> 2) + 4 * (lane >> 5);
            xz[((size_t)dir * MROWS + row) * G_ + col] = __float2bfloat16(acc[j][reg] + bv);
        }
    }
}

// ---------------- recurrent scan: gate-local, 3-tier rec residency (v / a / LDS) ------
__device__ inline float dot2f16(unsigned int rbits, unsigned int hbits, float acc) {
#if __has_builtin(__builtin_amdgcn_fdot2)
    return __builtin_amdgcn_fdot2(__builtin_bit_cast(v2h, rbits),
                                  __builtin_bit_cast(v2h, hbits), acc, false);
#else
    v2h r = __builtin_bit_cast(v2h, rbits);
    v2h h = __builtin_bit_cast(v2h, hbits);
    return acc + (float)r[0] * (float)h[0] + (float)r[1] * (float)h[1];
#endif
}

__device__ inline float sigmoidf(float x) { return 1.f / (1.f + __expf(-x)); }

// Pin a (compiler-loaded, waitcnt-tracked) dword into an AGPR. volatile anchors it in the
// preamble so it cannot be re-sunk into the loop (r4/r5 failure mode).
__device__ inline unsigned apin(unsigned v) {
    unsigned a;
    asm volatile("v_accvgpr_write_b32 %0, %1" : "=a"(a) : "v"(v));
    return a;
}
// Read an AGPR back into an arch VGPR (plain VALU move, 1 instr).
__device__ inline unsigned aread(unsigned a) {
    unsigned v;
    asm volatile("v_accvgpr_read_b32 %0, %1" : "=v"(v) : "a"(a));
    return v;
}

// r7 crash root-cause: 400 dwords of "=v"-pinned rec exceeded the 256 arch-VGPR class ->
// unallocatable -> fault. Fix: 3-tier residency sized to the register file.
//   tier V: kk 0..10  -> 44 uint4 = 176 dwords, asm global_load "=v" (r6-proven pattern)
//   tier A: kk 11..24 -> 56 uint4 = 224 dwords in AGPRs (apin/aread)
//   tier L: kk 25..31 -> 7 groups = 114.7 KB LDS
// Arch ~176+50=226<=256; acc 224<=256; total ~450<=512 (m08: spill-free through 450).
// LDS 115.7 KB -> 1 wg/CU -> 4 waves = 1/SIMD -> 512-reg budget (waves_per_eu(1) hint).
// 256 threads; thread t owns all 4 gate columns of h-index t (t, t+256, t+512, t+768):
// no z-exchange, 1 barrier/step, hv broadcasts 32/wave x 4 waves.
#define KKV 11
#define KKA 14
#define KKL 7
__global__ __launch_bounds__(256) __attribute__((amdgpu_waves_per_eu(1)))
void scan_kernel(
        const __hip_bfloat16* __restrict__ xz,    // [2][MROWS][G]
        const uint4* __restrict__ recQ,           // [2][32][1024] uint4
        const float* __restrict__ Wd,             // [S*H][2]
        const float* __restrict__ bd,             // [2]
        float* __restrict__ out) {                // [B][2], pre-zeroed
    int b = blockIdx.x, dir = blockIdx.y, tid = threadIdx.x;   // tid = h-index j
    __shared__ __align__(16) uint4 sh_rec[KKL * G_];     // 114688 B
    __shared__ __align__(16) _Float16 sh_h[2][H_];       // 1 KB, double-buffered h
    __shared__ float rbuf[8];

    const uint4* rqbase = recQ + (size_t)dir * 32768;

    // ---- tier V: asm-origin preload, kk 0..10, 4 gate columns ----
    u32x4 vi[KKV], vf[KKV], vc[KKV], vo[KKV];
    {
        unsigned long long ai = (unsigned long long)(const void*)(rqbase + tid);
        unsigned long long af = (unsigned long long)(const void*)(rqbase + tid + 256);
        unsigned long long ac = (unsigned long long)(const void*)(rqbase + tid + 512);
        unsigned long long ao = (unsigned long long)(const void*)(rqbase + tid + 768);
#pragma unroll
        for (int kk = 0; kk < KKV; ++kk) {
            unsigned long long o = (unsigned long long)kk * 16384ull;
            asm volatile("global_load_dwordx4 %0, %1, off" : "=v"(vi[kk]) : "v"(ai + o));
            asm volatile("global_load_dwordx4 %0, %1, off" : "=v"(vf[kk]) : "v"(af + o));
            asm volatile("global_load_dwordx4 %0, %1, off" : "=v"(vc[kk]) : "v"(ac + o));
            asm volatile("global_load_dwordx4 %0, %1, off" : "=v"(vo[kk]) : "v"(ao + o));
        }
        asm volatile("s_waitcnt vmcnt(0)" ::: "memory");
    }

    // ---- tier A: C++ load (compiler-tracked waitcnt) + AGPR pin, kk 11..24 ----
    unsigned agi[KKA][4], agf[KKA][4], agc[KKA][4], ago[KKA][4];
#pragma unroll
    for (int kk = 0; kk < KKA; ++kk) {
        const uint4* g = rqbase + (KKV + kk) * 1024 + tid;
        uint4 ti = g[0], tf = g[256], tc = g[512], to = g[768];
        agi[kk][0] = apin(ti.x); agi[kk][1] = apin(ti.y); agi[kk][2] = apin(ti.z); agi[kk][3] = apin(ti.w);
        agf[kk][0] = apin(tf.x); agf[kk][1] = apin(tf.y); agf[kk][2] = apin(tf.z); agf[kk][3] = apin(tf.w);
        agc[kk][0] = apin(tc.x); agc[kk][1] = apin(tc.y); agc[kk][2] = apin(tc.z); agc[kk][3] = apin(tc.w);
        ago[kk][0] = apin(to.x); ago[kk][1] = apin(to.y); ago[kk][2] = apin(to.z); ago[kk][3] = apin(to.w);
    }

    // ---- tier L: stage kk 25..31 into LDS (contiguous, coalesced: 28 uint4/thread) ----
#pragma unroll
    for (int j = 0; j < KKL * 4; ++j)
        sh_rec[j * 256 + tid] = rqbase[(KKV + KKA) * 1024 + j * 256 + tid];

    sh_h[0][tid] = (_Float16)0.f;
    float c = 0.f, pl0 = 0.f, pl1 = 0.f;
    const __hip_bfloat16* xzb = xz + ((size_t)dir * MROWS + (size_t)b * S_) * G_ + tid;
    __syncthreads();

    int p = 0;
    for (int s = 0; s < S_; ++s) {
        float xzi = __bfloat162float(xzb[(size_t)s * G_]);
        float xzf = __bfloat162float(xzb[(size_t)s * G_ + 256]);
        float xzc = __bfloat162float(xzb[(size_t)s * G_ + 512]);
        float xzo = __bfloat162float(xzb[(size_t)s * G_ + 768]);
        int t = dir ? (S_ - 1 - s) : s;
        float2 wv = ((const float2*)Wd)[t * H_ + tid];

        const uint4* hp = (const uint4*)&sh_h[p][0];          // 32 uint4 = 256 halves
        float zia = 0.f, zib = 0.f, zfa = 0.f, zfb = 0.f;
        float zca = 0.f, zcb = 0.f, zoa = 0.f, zob = 0.f;

        // tier V (kk 0..10): one hv broadcast feeds 16 dot2s
#pragma unroll
        for (int kk = 0; kk < KKV; ++kk) {
            uint4 hv = hp[kk];
            u32x4 ri = vi[kk], rf = vf[kk], rc = vc[kk], ro = vo[kk];
            zia = dot2f16(ri.x, hv.x, zia); zib = dot2f16(ri.y, hv.y, zib);
            zia = dot2f16(ri.z, hv.z, zia); zib = dot2f16(ri.w, hv.w, zib);
            zfa = dot2f16(rf.x, hv.x, zfa); zfb = dot2f16(rf.y, hv.y, zfb);
            zfa = dot2f16(rf.z, hv.z, zfa); zfb = dot2f16(rf.w, hv.w, zfb);
            zca = dot2f16(rc.x, hv.x, zca); zcb = dot2f16(rc.y, hv.y, zcb);
            zca = dot2f16(rc.z, hv.z, zca); zcb = dot2f16(rc.w, hv.w, zcb);
            zoa = dot2f16(ro.x, hv.x, zoa); zob = dot2f16(ro.y, hv.y, zob);
            zoa = dot2f16(ro.z, hv.z, zoa); zob = dot2f16(ro.w, hv.w, zob);
        }
        // tier A (kk 11..24): AGPR readback + dot2
#pragma unroll
        for (int kk = 0; kk < KKA; ++kk) {
            uint4 hv = hp[KKV + kk];
            zia = dot2f16(aread(agi[kk][0]), hv.x, zia); zib = dot2f16(aread(agi[kk][1]), hv.y, zib);
            zia = dot2f16(aread(agi[kk][2]), hv.z, zia); zib = dot2f16(aread(agi[kk][3]), hv.w, zib);
            zfa = dot2f16(aread(agf[kk][0]), hv.x, zfa); zfb = dot2f16(aread(agf[kk][1]), hv.y, zfb);
            zfa = dot2f16(aread(agf[kk][2]), hv.z, zfa); zfb = dot2f16(aread(agf[kk][3]), hv.w, zfb);
            zca = dot2f16(aread(agc[kk][0]), hv.x, zca); zcb = dot2f16(aread(agc[kk][1]), hv.y, zcb);
            zca = dot2f16(aread(agc[kk][2]), hv.z, zca); zcb = dot2f16(aread(agc[kk][3]), hv.w, zcb);
            zoa = dot2f16(aread(ago[kk][0]), hv.x, zoa); zob = dot2f16(aread(ago[kk][1]), hv.y, zob);
            zoa = dot2f16(aread(ago[kk][2]), hv.z, zoa); zob = dot2f16(aread(ago[kk][3]), hv.w, zob);
        }
        // tier L (kk 25..31)
#pragma unroll
        for (int j = 0; j < KKL; ++j) {
            uint4 hv = hp[KKV + KKA + j];
            uint4 ri = sh_rec[j * 1024 + tid];
            uint4 rf = sh_rec[j * 1024 + tid + 256];
            uint4 rc = sh_rec[j * 1024 + tid + 512];
            uint4 ro = sh_rec[j * 1024 + tid + 768];
            zia = dot2f16(ri.x, hv.x, zia); zib = dot2f16(ri.y, hv.y, zib);
            zia = dot2f16(ri.z, hv.z, zia); zib = dot2f16(ri.w, hv.w, zib);
            zfa = dot2f16(rf.x, hv.x, zfa); zfb = dot2f16(rf.y, hv.y, zfb);
            zfa = dot2f16(rf.z, hv.z, zfa); zfb = dot2f16(rf.w, hv.w, zfb);
            zca = dot2f16(rc.x, hv.x, zca); zcb = dot2f16(rc.y, hv.y, zcb);
            zca = dot2f16(rc.z, hv.z, zca); zcb = dot2f16(rc.w, hv.w, zcb);
            zoa = dot2f16(ro.x, hv.x, zoa); zob = dot2f16(ro.y, hv.y, zob);
            zoa = dot2f16(ro.z, hv.z, zoa); zob = dot2f16(ro.w, hv.w, zob);
        }

        // gates combine entirely in-register (no z exchange)
        float ig = sigmoidf(zia + zib + xzi);
        float fg = sigmoidf(zfa + zfb + xzf);
        float cc = fmaxf(zca + zcb + xzc, 0.f);
        float og = sigmoidf(zoa + zob + xzo);
        c = fg * c + ig * cc;
        float h = og * fmaxf(c, 0.f);
        sh_h[p ^ 1][tid] = (_Float16)h;                        // write NEXT buffer
        pl0 = fmaf(h, wv.x, pl0);
        pl1 = fmaf(h, wv.y, pl1);
        __syncthreads();                                       // single barrier per step
        p ^= 1;
    }

    // reduction over 256 threads (4 waves)
#pragma unroll
    for (int off = 32; off > 0; off >>= 1) {
        pl0 += __shfl_down(pl0, off);
        pl1 += __shfl_down(pl1, off);
    }
    if ((tid & 63) == 0) {
        int w = tid >> 6;
        rbuf[w] = pl0; rbuf[4 + w] = pl1;
    }
    __syncthreads();
    if (tid == 0) {
        float t0 = rbuf[0] + rbuf[1] + rbuf[2] + rbuf[3];
        float t1 = rbuf[4] + rbuf[5] + rbuf[6] + rbuf[7];
        atomicAdd(&out[b * 2 + 0], t0);
        atomicAdd(&out[b * 2 + 1], t1);
    }
    if (dir == 0 && tid < 2) atomicAdd(&out[b * 2 + tid], bd[tid]);
}

// ---------------- launch ----------------
extern "C" void kernel_launch(void* const* d_in, const int* in_sizes, int n_in,
                              void* d_out, int out_size, void* d_ws, size_t ws_size,
                              hipStream_t stream) {
    const float* x        = (const float*)d_in[0];
    const float* kernel_f = (const float*)d_in[1];
    const float* rec_f    = (const float*)d_in[2];
    const float* bias_f   = (const float*)d_in[3];
    const float* kernel_b = (const float*)d_in[4];
    const float* rec_b    = (const float*)d_in[5];
    const float* bias_b   = (const float*)d_in[6];
    const float* Wd       = (const float*)d_in[7];
    const float* bd       = (const float*)d_in[8];
    float* out = (float*)d_out;

    // workspace layout
    char* w = (char*)d_ws;
    __hip_bfloat16* xz  = (__hip_bfloat16*)w;                       // 2*32768*1024*2 = 134217728
    __hip_bfloat16* xbf = (__hip_bfloat16*)(w + 134217728);         // 64*512*768*2   = 50331648
    __hip_bfloat16* kT  = (__hip_bfloat16*)(w + 184549376);         // 2*1024*768*2   = 3145728
    unsigned int*  recQ = (unsigned int*) (w + 187695104);          // 2*32*1024*16   = 1048576

    // prep
    int nx = B_ * S_ * E_;
    cast_x_kernel<<<nx / (256 * 4), 256, 0, stream>>>(x, xbf, nx);
    prep_kT_kernel<<<dim3((E_ * G_) / 256, 2), 256, 0, stream>>>(kernel_f, kernel_b, kT);
    prep_recQ_kernel<<<dim3(131072 / 256, 2), 256, 0, stream>>>(rec_f, rec_b, recQ);

    // xz GEMM: grid (N/128, M/128, dirs)
    gemm_xz_kernel<<<dim3(G_ / TN, MROWS / TM, 2), 256, 0, stream>>>(xbf, kT, bias_f, bias_b, xz);

    // zero logits, then scan accumulates
    hipMemsetAsync(d_out, 0, (size_t)out_size * sizeof(float), stream);
    scan_kernel<<<dim3(B_, 2), 256, 0, stream>>>(xz, (const uint4*)recQ, Wd, bd, out);
}